// Round 7
// baseline (305.155 us; speedup 1.0000x reference)
//
#include <hip/hip_runtime.h>
#include <stdint.h>

// Problem constants (fixed by the reference setup)
#define B_ 32
#define I_ 16384
#define H_ 1024
#define T_ 10
#define M_ 320   // T_*B_  (GEMM M dimension, m = t*32 + b)

typedef __attribute__((ext_vector_type(8))) short short8;  // 8 bf16 (4 VGPRs)
typedef __attribute__((ext_vector_type(4))) float f32x4;
typedef __attribute__((ext_vector_type(4))) unsigned int u32x4;

// RNE round fp32 bits -> bf16 (upper 16)
__device__ __forceinline__ unsigned int rne16(unsigned int u) {
  return (u + 0x7FFFu + ((u >> 16) & 1u)) >> 16;
}

// ---------------------------------------------------------------------------
// Kernel 1: pack spikes [B][I][T] f32 -> Sbf [M=T*B][I] bf16 (exact: 0/1)
// (unchanged from R6 — verified) No LDS; coalesced 16B stores.
// ---------------------------------------------------------------------------
__global__ __launch_bounds__(640) void pack_s(const float* __restrict__ spikes,
                                              uint16_t* __restrict__ Sbf) {
  const int b = blockIdx.x & 31, imac = blockIdx.x >> 5;
  const int t = threadIdx.x >> 6, lane = threadIdx.x & 63;
  const int i0 = imac * 512 + lane * 8;
  const float* sp = spikes + (size_t)b * (I_ * T_) + (size_t)i0 * T_ + t;
  unsigned int w[4];
#pragma unroll
  for (int p = 0; p < 4; p++) {
    union { float f; unsigned int u; } c0, c1;
    c0.f = sp[(2 * p) * T_];
    c1.f = sp[(2 * p + 1) * T_];
    w[p] = (c0.u >> 16) | (c1.u & 0xFFFF0000u);  // trunc: exact for 0.0/1.0
  }
  const int m = t * 32 + b;
  *(u32x4*)&Sbf[(size_t)m * I_ + i0] = u32x4{w[0], w[1], w[2], w[3]};
}

// ---------------------------------------------------------------------------
// Kernel 1b: split_t — W,S [I][H] fp32 -> WhiT, WloT [H][I] bf16 (TRANSPOSED).
// hi = RNE(w*s), lo = RNE(w*s - hi) — the exact bit recipe of the passing
// rounds (correctness cliff: do not change). Done ONCE here instead of 16x
// redundantly inside the GEMM (R6's mistake). 64x64 LDS tile transpose;
// streaming BW-bound.
// ---------------------------------------------------------------------------
__global__ __launch_bounds__(256) void split_t(const float* __restrict__ Wg,
                                               const float* __restrict__ Sg,
                                               uint16_t* __restrict__ WhiT,
                                               uint16_t* __restrict__ WloT) {
  __shared__ __align__(16) uint16_t thi[64 * 72];  // [h][i], pad 64->72
  __shared__ __align__(16) uint16_t tlo[64 * 72];
  const int it = blockIdx.x & 255, ht = blockIdx.x >> 8;
  const int i0 = it * 64, h0 = ht * 64;
#pragma unroll
  for (int p = 0; p < 4; p++) {
    int e = p * 256 + threadIdx.x;
    int i = e >> 4, hq = e & 15;
    size_t g = (size_t)(i0 + i) * H_ + h0 + hq * 4;
    f32x4 wv = *(const f32x4*)&Wg[g];
    f32x4 sv = *(const f32x4*)&Sg[g];
    float pr[4] = {wv.x * sv.x, wv.y * sv.y, wv.z * sv.z, wv.w * sv.w};
#pragma unroll
    for (int j = 0; j < 4; j++) {
      union { float f; unsigned int u; } cv; cv.f = pr[j];
      unsigned int hb = rne16(cv.u);
      union { unsigned int u; float f; } hv; hv.u = hb << 16;
      union { float f; unsigned int u; } cl; cl.f = pr[j] - hv.f;  // exact
      unsigned int lb = rne16(cl.u);
      thi[(hq * 4 + j) * 72 + i] = (uint16_t)hb;
      tlo[(hq * 4 + j) * 72 + i] = (uint16_t)lb;
    }
  }
  __syncthreads();
#pragma unroll
  for (int p = 0; p < 2; p++) {
    int e = p * 256 + threadIdx.x;
    int h = e >> 3, c = e & 7;
    u32x4 vh = *(const u32x4*)&thi[h * 72 + c * 8];
    u32x4 vl = *(const u32x4*)&tlo[h * 72 + c * 8];
    *(u32x4*)&WhiT[(size_t)(h0 + h) * I_ + i0 + c * 8] = vh;
    *(u32x4*)&WloT[(size_t)(h0 + h) * I_ + i0 + c * 8] = vl;
  }
}

// ---------------------------------------------------------------------------
// Kernel 2: GEMM (planes path)  partial[ks][320][1024] = Sbf * (hi + lo)
// NO LDS, NO BARRIERS. Both A and B fragments are straight 16B k-contiguous
// global loads (B from the transposed planes). Per wave per stage (BK=32):
// 5 A + 8 B dwordx4 loads, 40 MFMA. Depth-2 register pipeline ->
// fine-grained per-wave vmcnt waits only. Block = 4 waves; wave owns
// m [80w,80w+80) x n 64 (5x4 tiles, 80 acc VGPR). Grid = 16 nt x KS,
// ks fastest (co-resident blocks share the Sbf slice in LLC).
// Accumulation order bit-identical to the passing rounds: ascending k-stage;
// hi-MFMA then lo-MFMA per 32-k block per element.
// ---------------------------------------------------------------------------
__global__ __launch_bounds__(256, 2) void gemm_p(const uint16_t* __restrict__ Sbf,
                                                 const uint16_t* __restrict__ WhiT,
                                                 const uint16_t* __restrict__ WloT,
                                                 float* __restrict__ partial,
                                                 int kchunk, int kslog) {
  const int ks = blockIdx.x & ((1 << kslog) - 1);
  const int nt = blockIdx.x >> kslog;          // 0..15
  const int nbase = nt * 64;
  const int tid = threadIdx.x;
  const int lane = tid & 63, wid = tid >> 6;   // wid 0..3
  const int quad = lane >> 4, l15 = lane & 15;
  const int kofs = ks * kchunk;
  const int stages = kchunk >> 5;              // BK = 32; even, >= 4

  // A: lane holds A[m=wid*80+tm*16+l15][k=quad*8+j] -> 16B contiguous
  const uint16_t* ap = Sbf + (size_t)(wid * 80 + l15) * I_ + quad * 8 + kofs;
  // B: lane holds Bt[n=nbase+tn*16+l15][k=quad*8+j] -> 16B contiguous
  const size_t brow = (size_t)(nbase + l15) * I_ + quad * 8 + kofs;
  const uint16_t* bhp = WhiT + brow;
  const uint16_t* blp = WloT + brow;

  f32x4 acc[5][4];
#pragma unroll
  for (int a = 0; a < 5; a++)
#pragma unroll
    for (int b = 0; b < 4; b++) acc[a][b] = f32x4{0.f, 0.f, 0.f, 0.f};

  u32x4 af0[5], af1[5], bh0[4], bh1[4], bl0[4], bl1[4];

#define LOADS(af, bh_, bl_, sk)                                             \
  {                                                                         \
    const size_t ko = (size_t)(sk) * 32;                                    \
    _Pragma("unroll")                                                       \
    for (int tm = 0; tm < 5; tm++)                                          \
      af[tm] = *(const u32x4*)(ap + (size_t)tm * 16 * I_ + ko);             \
    _Pragma("unroll")                                                       \
    for (int tn = 0; tn < 4; tn++) {                                        \
      bh_[tn] = *(const u32x4*)(bhp + (size_t)tn * 16 * I_ + ko);           \
      bl_[tn] = *(const u32x4*)(blp + (size_t)tn * 16 * I_ + ko);           \
    }                                                                       \
  }

#define COMPUTE(af, bh_, bl_)                                               \
  {                                                                         \
    _Pragma("unroll")                                                       \
    for (int tn = 0; tn < 4; tn++) {                                        \
      short8 bhi = __builtin_bit_cast(short8, bh_[tn]);                     \
      short8 blo = __builtin_bit_cast(short8, bl_[tn]);                     \
      _Pragma("unroll")                                                     \
      for (int tm = 0; tm < 5; tm++) {                                      \
        short8 av = __builtin_bit_cast(short8, af[tm]);                     \
        acc[tm][tn] = __builtin_amdgcn_mfma_f32_16x16x32_bf16(av, bhi, acc[tm][tn], 0, 0, 0); \
        acc[tm][tn] = __builtin_amdgcn_mfma_f32_16x16x32_bf16(av, blo, acc[tm][tn], 0, 0, 0); \
      }                                                                     \
    }                                                                       \
  }

  LOADS(af0, bh0, bl0, 0);
  LOADS(af1, bh1, bl1, 1);
  int s = 0;
  for (; s + 2 < stages; s += 2) {
    COMPUTE(af0, bh0, bl0);
    LOADS(af0, bh0, bl0, s + 2);
    COMPUTE(af1, bh1, bl1);
    LOADS(af1, bh1, bl1, s + 3);
  }
  COMPUTE(af0, bh0, bl0);
  COMPUTE(af1, bh1, bl1);
#undef LOADS
#undef COMPUTE

  // epilogue: C/D layout col=lane&15, row=quad*4+reg
#pragma unroll
  for (int tm = 0; tm < 5; tm++)
#pragma unroll
    for (int tn = 0; tn < 4; tn++) {
      int mrow = wid * 80 + tm * 16 + quad * 4;
      int ncol = nbase + tn * 16 + l15;
      float* dst = partial + ((size_t)ks * M_ + mrow) * H_ + ncol;
      dst[0 * H_] = acc[tm][tn].x;
      dst[1 * H_] = acc[tm][tn].y;
      dst[2 * H_] = acc[tm][tn].z;
      dst[3 * H_] = acc[tm][tn].w;
    }
}

// ---------------------------------------------------------------------------
// Kernel 2-FALLBACK: exact R6 gemm (in-register split, NW=32) — used only if
// ws_size cannot hold the transposed planes. Known-passing at ws >= 34 MB.
// ---------------------------------------------------------------------------
__global__ __launch_bounds__(256) void gemm_fb(const uint16_t* __restrict__ Sbf,
                                               const float* __restrict__ Wg,
                                               const float* __restrict__ Sg,
                                               float* __restrict__ partial,
                                               int kchunk, int kslog) {
  const int ks = blockIdx.x & ((1 << kslog) - 1);
  const int nt = blockIdx.x >> kslog;
  const int nbase = nt * 32;
  const int tid = threadIdx.x;
  const int lane = tid & 63, wid = tid >> 6;
  const int quad = lane >> 4, l15 = lane & 15;
  const int kofs = ks * kchunk;
  const int stages = kchunk >> 5;

  const uint16_t* ap = Sbf + (size_t)(wid * 80 + l15) * I_ + quad * 8 + kofs;
  const size_t boff = (size_t)(kofs + quad * 8) * H_ + nbase + l15;
  const float* wp = Wg + boff;
  const float* sp = Sg + boff;

  f32x4 acc[5][2];
#pragma unroll
  for (int a = 0; a < 5; a++)
#pragma unroll
    for (int b = 0; b < 2; b++) acc[a][b] = f32x4{0.f, 0.f, 0.f, 0.f};

  u32x4 af0[5], af1[5];
  float wv0[2][8], sv0[2][8], wv1[2][8], sv1[2][8];

#define LOADS(af, wv, sv, sk)                                               \
  {                                                                         \
    const size_t ko = (size_t)(sk) * 32;                                    \
    _Pragma("unroll")                                                       \
    for (int tm = 0; tm < 5; tm++)                                          \
      af[tm] = *(const u32x4*)(ap + (size_t)tm * 16 * I_ + ko);             \
    _Pragma("unroll")                                                       \
    for (int tn = 0; tn < 2; tn++)                                          \
      _Pragma("unroll")                                                     \
      for (int j = 0; j < 8; j++) {                                         \
        size_t o = (ko + j) * H_ + tn * 16;                                 \
        wv[tn][j] = wp[o];                                                  \
        sv[tn][j] = sp[o];                                                  \
      }                                                                     \
  }

#define COMPUTE(af, wv, sv)                                                 \
  {                                                                         \
    _Pragma("unroll")                                                       \
    for (int tn = 0; tn < 2; tn++) {                                        \
      unsigned int hw[4], lw[4];                                            \
      _Pragma("unroll")                                                     \
      for (int p = 0; p < 4; p++) {                                         \
        unsigned int hu[2], lu[2];                                          \
        _Pragma("unroll")                                                   \
        for (int e = 0; e < 2; e++) {                                       \
          float pr = wv[tn][2 * p + e] * sv[tn][2 * p + e];                 \
          union { float f; unsigned int u; } cv; cv.f = pr;                 \
          unsigned int r = rne16(cv.u) << 16;                               \
          union { unsigned int u; float f; } hv; hv.u = r;                  \
          union { float f; unsigned int u; } cl; cl.f = pr - hv.f;          \
          unsigned int rl = rne16(cl.u) << 16;                              \
          hu[e] = r; lu[e] = rl;                                            \
        }                                                                   \
        hw[p] = (hu[0] >> 16) | (hu[1] & 0xFFFF0000u);                      \
        lw[p] = (lu[0] >> 16) | (lu[1] & 0xFFFF0000u);                      \
      }                                                                     \
      short8 bhi = __builtin_bit_cast(short8, u32x4{hw[0], hw[1], hw[2], hw[3]}); \
      short8 blo = __builtin_bit_cast(short8, u32x4{lw[0], lw[1], lw[2], lw[3]}); \
      _Pragma("unroll")                                                     \
      for (int tm = 0; tm < 5; tm++) {                                      \
        short8 av = __builtin_bit_cast(short8, af[tm]);                     \
        acc[tm][tn] = __builtin_amdgcn_mfma_f32_16x16x32_bf16(av, bhi, acc[tm][tn], 0, 0, 0); \
        acc[tm][tn] = __builtin_amdgcn_mfma_f32_16x16x32_bf16(av, blo, acc[tm][tn], 0, 0, 0); \
      }                                                                     \
    }                                                                       \
  }

  LOADS(af0, wv0, sv0, 0);
  LOADS(af1, wv1, sv1, 1);
  int s = 0;
  for (; s + 2 < stages; s += 2) {
    COMPUTE(af0, wv0, sv0);
    LOADS(af0, wv0, sv0, s + 2);
    COMPUTE(af1, wv1, sv1);
    LOADS(af1, wv1, sv1, s + 3);
  }
  COMPUTE(af0, wv0, sv0);
  COMPUTE(af1, wv1, sv1);
#undef LOADS
#undef COMPUTE

#pragma unroll
  for (int tm = 0; tm < 5; tm++)
#pragma unroll
    for (int tn = 0; tn < 2; tn++) {
      int mrow = wid * 80 + tm * 16 + quad * 4;
      int ncol = nbase + tn * 16 + l15;
      float* dst = partial + ((size_t)ks * M_ + mrow) * H_ + ncol;
      dst[0 * H_] = acc[tm][tn].x;
      dst[1 * H_] = acc[tm][tn].y;
      dst[2 * H_] = acc[tm][tn].z;
      dst[3 * H_] = acc[tm][tn].w;
    }
}

// ---------------------------------------------------------------------------
// Kernel 3: deterministic reduction of K-split partials -> weighted [320][1024]
// Ascending-ks order (bit-identical across rounds). Also zeroes diag region.
// ---------------------------------------------------------------------------
__global__ __launch_bounds__(256) void reduce_w(const float* __restrict__ partial,
                                                float* __restrict__ weighted,
                                                float* __restrict__ out, int KS) {
  if (blockIdx.x == 0 && threadIdx.x < 30) out[327680 + threadIdx.x] = 0.f;
  int j = (blockIdx.x * 256 + threadIdx.x) * 4;
  f32x4 s = f32x4{0.f, 0.f, 0.f, 0.f};
  for (int k = 0; k < KS; k++) {
    f32x4 p = *(const f32x4*)&partial[(size_t)k * (M_ * H_) + j];
    s += p;
  }
  *(f32x4*)&weighted[j] = s;
}

// ---------------------------------------------------------------------------
// Kernel 4: LIF scan (unchanged from R6 — verified). Barrier-free; thread
// owns h and 4 batches; per-h threshold chain deterministic across lanes.
// ---------------------------------------------------------------------------
__global__ __launch_bounds__(64) void scan(const float* __restrict__ weighted,
                                           const float* __restrict__ threshold,
                                           const float* __restrict__ fre0,
                                           const float* __restrict__ p_tau_mem,
                                           const float* __restrict__ p_tau_syn,
                                           const float* __restrict__ p_target,
                                           const float* __restrict__ p_lr,
                                           float* __restrict__ out) {
  const int lane = threadIdx.x;
  const int hl = lane & 7, bg = lane >> 3;
  const int h = blockIdx.x * 8 + hl;
  const float alpha_mem = expf(-0.001f / p_tau_mem[0]);
  const float alpha_syn = expf(-0.001f / p_tau_syn[0]);
  const float target = p_target[0], lr = p_lr[0];
  float v[4], isyn[4];
#pragma unroll
  for (int j = 0; j < 4; j++) { v[j] = 0.f; isyn[j] = 0.f; }
  float fre = fre0[h];
  float thr = threshold[h];
  for (int t = 0; t < T_; t++) {
    float rsum = 0.f, vsum = 0.f;
#pragma unroll
    for (int j = 0; j < 4; j++) {
      int b = bg * 4 + j;
      float w_in = weighted[(size_t)(t * 32 + b) * H_ + h];
      isyn[j] = alpha_syn * isyn[j] + w_in;
      v[j] = alpha_mem * v[j] + isyn[j];
      float spike = (v[j] >= thr) ? 1.f : 0.f;
      v[j] -= spike * thr;
      out[(size_t)b * (H_ * T_) + (size_t)h * T_ + t] = spike;
      rsum += spike;
      vsum += v[j];
    }
    float r = rsum;
    r += __shfl_xor(r, 8);
    r += __shfl_xor(r, 16);
    r += __shfl_xor(r, 32);
    float rate = r * (1.f / 32.f);
    fre = 0.99f * fre + 0.01f * rate;
    thr = thr + lr * (fre - target);
    float vv = vsum, rr = rate, tt = thr;
#pragma unroll
    for (int off = 32; off >= 1; off >>= 1) {
      vv += __shfl_xor(vv, off);
      rr += __shfl_xor(rr, off);
      tt += __shfl_xor(tt, off);
    }
    if (lane == 0) {
      atomicAdd(&out[327680 + t], vv * (1.f / 32768.f));
      atomicAdd(&out[327690 + t], rr * (1.f / 8192.f));
      atomicAdd(&out[327700 + t], tt * (1.f / 8192.f));
    }
  }
}

// ---------------------------------------------------------------------------
extern "C" void kernel_launch(void* const* d_in, const int* in_sizes, int n_in,
                              void* d_out, int out_size, void* d_ws, size_t ws_size,
                              hipStream_t stream) {
  const float* spikes    = (const float*)d_in[0];
  const float* weight    = (const float*)d_in[1];
  const float* strength  = (const float*)d_in[2];
  const float* threshold = (const float*)d_in[3];
  const float* fre0      = (const float*)d_in[4];
  const float* tau_mem   = (const float*)d_in[5];
  const float* tau_syn   = (const float*)d_in[6];
  const float* target    = (const float*)d_in[7];
  const float* lr        = (const float*)d_in[8];
  float* out = (float*)d_out;

  const size_t sbf_bytes = (size_t)M_ * I_ * 2;     // 10.5 MB
  const size_t plane     = (size_t)I_ * H_ * 2;     // 33.6 MB per bf16 plane
  const size_t slice     = (size_t)M_ * H_ * 4;     // 1.31 MB per K-partial

  // planes path: Sbf | WhiT | WloT | partial[KS] | weighted
  int KS = 32, kslog = 5;
  while (KS > 1 &&
         sbf_bytes + 2 * plane + (size_t)(KS + 1) * slice > ws_size) {
    KS >>= 1; kslog--;
  }
  bool use_planes =
      sbf_bytes + 2 * plane + (size_t)(KS + 1) * slice <= ws_size;

  if (use_planes) {
    uint16_t* Sbf   = (uint16_t*)d_ws;
    uint16_t* WhiT  = (uint16_t*)((char*)d_ws + sbf_bytes);
    uint16_t* WloT  = (uint16_t*)((char*)d_ws + sbf_bytes + plane);
    float* partial  = (float*)((char*)d_ws + sbf_bytes + 2 * plane);
    float* weighted = (float*)((char*)d_ws + sbf_bytes + 2 * plane +
                               (size_t)KS * slice);
    pack_s<<<32 * (I_ / 512), 640, 0, stream>>>(spikes, Sbf);
    split_t<<<(I_ / 64) * (H_ / 64), 256, 0, stream>>>(weight, strength,
                                                       WhiT, WloT);
    gemm_p<<<16 * KS, 256, 0, stream>>>(Sbf, WhiT, WloT, partial,
                                        I_ / KS, kslog);
    reduce_w<<<(M_ * H_) / 1024, 256, 0, stream>>>(partial, weighted, out, KS);
    scan<<<H_ / 8, 64, 0, stream>>>(weighted, threshold, fre0, tau_mem,
                                    tau_syn, target, lr, out);
  } else {
    // fallback: exact R6 structure (known-passing at ws >= 34 MB)
    int KSf = 16, kslogf = 4;
    while (KSf > 1 &&
           sbf_bytes + (size_t)(KSf + 1) * slice > ws_size) {
      KSf >>= 1; kslogf--;
    }
    uint16_t* Sbf   = (uint16_t*)d_ws;
    float* partial  = (float*)((char*)d_ws + sbf_bytes);
    float* weighted = (float*)((char*)d_ws + sbf_bytes + (size_t)KSf * slice);
    pack_s<<<32 * (I_ / 512), 640, 0, stream>>>(spikes, Sbf);
    gemm_fb<<<32 * KSf, 256, 0, stream>>>(Sbf, weight, strength, partial,
                                          I_ / KSf, kslogf);
    reduce_w<<<(M_ * H_) / 1024, 256, 0, stream>>>(partial, weighted, out, KSf);
    scan<<<H_ / 8, 64, 0, stream>>>(weighted, threshold, fre0, tau_mem,
                                    tau_syn, target, lr, out);
  }
}

// Round 8
// 288.871 us; speedup vs baseline: 1.0564x; 1.0564x over previous
//
#include <hip/hip_runtime.h>
#include <stdint.h>

// Problem constants (fixed by the reference setup)
#define B_ 32
#define I_ 16384
#define H_ 1024
#define T_ 10
#define M_ 320   // T_*B_  (GEMM M dimension, m = t*32 + b)

typedef __attribute__((ext_vector_type(8))) short short8;  // 8 bf16 (4 VGPRs)
typedef __attribute__((ext_vector_type(4))) float f32x4;
typedef __attribute__((ext_vector_type(4))) unsigned int u32x4;

// RNE round fp32 bits -> bf16 (upper 16)
__device__ __forceinline__ unsigned int rne16(unsigned int u) {
  return (u + 0x7FFFu + ((u >> 16) & 1u)) >> 16;
}

// ---------------------------------------------------------------------------
// Kernel 1 (fused prep): blocks [0,1024) pack spikes -> Sbf bf16 [M][I];
// blocks [1024,5120) compute hi/lo bf16 split of weight*strength TRANSPOSED
// -> WhiT, WloT [H][I].
// Split recipe (correctness cliff — do not change): hi = RNE(w*s),
// lo = RNE(w*s - hi); identical bits to all passing rounds.
// LDS: ONE combined u32 tile (hi | lo<<16), row stride 65 (65 mod 32 = 1):
//  - phase-1 writes: bank = (4*hq + j + i) mod 32 -> exactly 2-way (free)
//  - phase-2 reads (b32): bank = (h + 8c + q) mod 32 -> 32 distinct, clean
// (R7's separate uint16 tiles at stride 72 gave ~16-way -> 7.6M conflicts.)
// ---------------------------------------------------------------------------
__global__ __launch_bounds__(256) void prep(const float* __restrict__ spikes,
                                            const float* __restrict__ Wg,
                                            const float* __restrict__ Sg,
                                            uint16_t* __restrict__ Sbf,
                                            uint16_t* __restrict__ WhiT,
                                            uint16_t* __restrict__ WloT) {
  const int tid = threadIdx.x;
  if (blockIdx.x < 1024) {
    // ---- pack: block = (b, i-macro of 512) ----
    const int b = blockIdx.x & 31, imac = blockIdx.x >> 5;
    const int it8 = tid & 63, tg = tid >> 6;       // 64 i-octets x 4 t-groups
    const int i0 = imac * 512 + it8 * 8;
    const float* spb = spikes + (size_t)b * (I_ * T_) + (size_t)i0 * T_;
#pragma unroll
    for (int tt = 0; tt < 3; tt++) {
      int t = tg + 4 * tt;                         // {tg, tg+4, tg+8}
      if (t < T_) {
        const float* sp = spb + t;
        unsigned int w[4];
#pragma unroll
        for (int p = 0; p < 4; p++) {
          union { float f; unsigned int u; } c0, c1;
          c0.f = sp[(2 * p) * T_];
          c1.f = sp[(2 * p + 1) * T_];
          w[p] = (c0.u >> 16) | (c1.u & 0xFFFF0000u);  // trunc: exact 0/1
        }
        *(u32x4*)&Sbf[(size_t)(t * 32 + b) * I_ + i0] =
            u32x4{w[0], w[1], w[2], w[3]};
      }
    }
    return;
  }
  // ---- split+transpose: 64i x 64h tile ----
  __shared__ unsigned int tile[64 * 65];           // [h][i] u32 = hi | lo<<16
  const int blk = blockIdx.x - 1024;
  const int it = blk & 255, ht = blk >> 8;
  const int i0 = it * 64, h0 = ht * 64;
#pragma unroll
  for (int p = 0; p < 4; p++) {
    int e = p * 256 + tid;
    int i = e >> 4, hq = e & 15;
    size_t g = (size_t)(i0 + i) * H_ + h0 + hq * 4;
    f32x4 wv = *(const f32x4*)&Wg[g];
    f32x4 sv = *(const f32x4*)&Sg[g];
    float pr[4] = {wv.x * sv.x, wv.y * sv.y, wv.z * sv.z, wv.w * sv.w};
#pragma unroll
    for (int j = 0; j < 4; j++) {
      union { float f; unsigned int u; } cv; cv.f = pr[j];
      unsigned int hb = rne16(cv.u);
      union { unsigned int u; float f; } hv; hv.u = hb << 16;
      union { float f; unsigned int u; } cl; cl.f = pr[j] - hv.f;  // exact
      unsigned int lb = rne16(cl.u);
      tile[(hq * 4 + j) * 65 + i] = hb | (lb << 16);
    }
  }
  __syncthreads();
#pragma unroll
  for (int p = 0; p < 2; p++) {
    int e = p * 256 + tid;
    int h = e >> 3, c = e & 7;                     // 8 consecutive i-octets
    const unsigned int* row = &tile[h * 65 + c * 8];
    unsigned int hw[4], lw[4];
#pragma unroll
    for (int q = 0; q < 4; q++) {
      unsigned int w0 = row[2 * q], w1 = row[2 * q + 1];
      hw[q] = (w0 & 0xFFFFu) | (w1 << 16);
      lw[q] = (w0 >> 16) | (w1 & 0xFFFF0000u);
    }
    size_t o = (size_t)(h0 + h) * I_ + i0 + c * 8;
    *(u32x4*)&WhiT[o] = u32x4{hw[0], hw[1], hw[2], hw[3]};
    *(u32x4*)&WloT[o] = u32x4{lw[0], lw[1], lw[2], lw[3]};
  }
}

// ---------------------------------------------------------------------------
// Kernel 2: GEMM (planes path) — UNCHANGED from R7 (passed, <70 µs).
// NO LDS, NO BARRIERS; A and B fragments are straight 16B k-contiguous
// global loads; depth-2 register pipeline; 40 MFMA/wave/stage.
// Accumulation order bit-identical to passing rounds.
// ---------------------------------------------------------------------------
__global__ __launch_bounds__(256, 2) void gemm_p(const uint16_t* __restrict__ Sbf,
                                                 const uint16_t* __restrict__ WhiT,
                                                 const uint16_t* __restrict__ WloT,
                                                 float* __restrict__ partial,
                                                 int kchunk, int kslog) {
  const int ks = blockIdx.x & ((1 << kslog) - 1);
  const int nt = blockIdx.x >> kslog;          // 0..15
  const int nbase = nt * 64;
  const int tid = threadIdx.x;
  const int lane = tid & 63, wid = tid >> 6;   // wid 0..3
  const int quad = lane >> 4, l15 = lane & 15;
  const int kofs = ks * kchunk;
  const int stages = kchunk >> 5;              // BK = 32; even, >= 4

  const uint16_t* ap = Sbf + (size_t)(wid * 80 + l15) * I_ + quad * 8 + kofs;
  const size_t brow = (size_t)(nbase + l15) * I_ + quad * 8 + kofs;
  const uint16_t* bhp = WhiT + brow;
  const uint16_t* blp = WloT + brow;

  f32x4 acc[5][4];
#pragma unroll
  for (int a = 0; a < 5; a++)
#pragma unroll
    for (int b = 0; b < 4; b++) acc[a][b] = f32x4{0.f, 0.f, 0.f, 0.f};

  u32x4 af0[5], af1[5], bh0[4], bh1[4], bl0[4], bl1[4];

#define LOADS(af, bh_, bl_, sk)                                             \
  {                                                                         \
    const size_t ko = (size_t)(sk) * 32;                                    \
    _Pragma("unroll")                                                       \
    for (int tm = 0; tm < 5; tm++)                                          \
      af[tm] = *(const u32x4*)(ap + (size_t)tm * 16 * I_ + ko);             \
    _Pragma("unroll")                                                       \
    for (int tn = 0; tn < 4; tn++) {                                        \
      bh_[tn] = *(const u32x4*)(bhp + (size_t)tn * 16 * I_ + ko);           \
      bl_[tn] = *(const u32x4*)(blp + (size_t)tn * 16 * I_ + ko);           \
    }                                                                       \
  }

#define COMPUTE(af, bh_, bl_)                                               \
  {                                                                         \
    _Pragma("unroll")                                                       \
    for (int tn = 0; tn < 4; tn++) {                                        \
      short8 bhi = __builtin_bit_cast(short8, bh_[tn]);                     \
      short8 blo = __builtin_bit_cast(short8, bl_[tn]);                     \
      _Pragma("unroll")                                                     \
      for (int tm = 0; tm < 5; tm++) {                                      \
        short8 av = __builtin_bit_cast(short8, af[tm]);                     \
        acc[tm][tn] = __builtin_amdgcn_mfma_f32_16x16x32_bf16(av, bhi, acc[tm][tn], 0, 0, 0); \
        acc[tm][tn] = __builtin_amdgcn_mfma_f32_16x16x32_bf16(av, blo, acc[tm][tn], 0, 0, 0); \
      }                                                                     \
    }                                                                       \
  }

  LOADS(af0, bh0, bl0, 0);
  LOADS(af1, bh1, bl1, 1);
  int s = 0;
  for (; s + 2 < stages; s += 2) {
    COMPUTE(af0, bh0, bl0);
    LOADS(af0, bh0, bl0, s + 2);
    COMPUTE(af1, bh1, bl1);
    LOADS(af1, bh1, bl1, s + 3);
  }
  COMPUTE(af0, bh0, bl0);
  COMPUTE(af1, bh1, bl1);
#undef LOADS
#undef COMPUTE

#pragma unroll
  for (int tm = 0; tm < 5; tm++)
#pragma unroll
    for (int tn = 0; tn < 4; tn++) {
      int mrow = wid * 80 + tm * 16 + quad * 4;
      int ncol = nbase + tn * 16 + l15;
      float* dst = partial + ((size_t)ks * M_ + mrow) * H_ + ncol;
      dst[0 * H_] = acc[tm][tn].x;
      dst[1 * H_] = acc[tm][tn].y;
      dst[2 * H_] = acc[tm][tn].z;
      dst[3 * H_] = acc[tm][tn].w;
    }
}

// ---------------------------------------------------------------------------
// Kernel 2-FALLBACK: exact R6 gemm (in-register split, NW=32) — only if
// ws_size cannot hold the transposed planes. Known-passing at ws >= 34 MB.
// ---------------------------------------------------------------------------
__global__ __launch_bounds__(256) void gemm_fb(const uint16_t* __restrict__ Sbf,
                                               const float* __restrict__ Wg,
                                               const float* __restrict__ Sg,
                                               float* __restrict__ partial,
                                               int kchunk, int kslog) {
  const int ks = blockIdx.x & ((1 << kslog) - 1);
  const int nt = blockIdx.x >> kslog;
  const int nbase = nt * 32;
  const int tid = threadIdx.x;
  const int lane = tid & 63, wid = tid >> 6;
  const int quad = lane >> 4, l15 = lane & 15;
  const int kofs = ks * kchunk;
  const int stages = kchunk >> 5;

  const uint16_t* ap = Sbf + (size_t)(wid * 80 + l15) * I_ + quad * 8 + kofs;
  const size_t boff = (size_t)(kofs + quad * 8) * H_ + nbase + l15;
  const float* wp = Wg + boff;
  const float* sp = Sg + boff;

  f32x4 acc[5][2];
#pragma unroll
  for (int a = 0; a < 5; a++)
#pragma unroll
    for (int b = 0; b < 2; b++) acc[a][b] = f32x4{0.f, 0.f, 0.f, 0.f};

  u32x4 af0[5], af1[5];
  float wv0[2][8], sv0[2][8], wv1[2][8], sv1[2][8];

#define LOADS(af, wv, sv, sk)                                               \
  {                                                                         \
    const size_t ko = (size_t)(sk) * 32;                                    \
    _Pragma("unroll")                                                       \
    for (int tm = 0; tm < 5; tm++)                                          \
      af[tm] = *(const u32x4*)(ap + (size_t)tm * 16 * I_ + ko);             \
    _Pragma("unroll")                                                       \
    for (int tn = 0; tn < 2; tn++)                                          \
      _Pragma("unroll")                                                     \
      for (int j = 0; j < 8; j++) {                                         \
        size_t o = (ko + j) * H_ + tn * 16;                                 \
        wv[tn][j] = wp[o];                                                  \
        sv[tn][j] = sp[o];                                                  \
      }                                                                     \
  }

#define COMPUTE(af, wv, sv)                                                 \
  {                                                                         \
    _Pragma("unroll")                                                       \
    for (int tn = 0; tn < 2; tn++) {                                        \
      unsigned int hw[4], lw[4];                                            \
      _Pragma("unroll")                                                     \
      for (int p = 0; p < 4; p++) {                                         \
        unsigned int hu[2], lu[2];                                          \
        _Pragma("unroll")                                                   \
        for (int e = 0; e < 2; e++) {                                       \
          float pr = wv[tn][2 * p + e] * sv[tn][2 * p + e];                 \
          union { float f; unsigned int u; } cv; cv.f = pr;                 \
          unsigned int r = rne16(cv.u) << 16;                               \
          union { unsigned int u; float f; } hv; hv.u = r;                  \
          union { float f; unsigned int u; } cl; cl.f = pr - hv.f;          \
          unsigned int rl = rne16(cl.u) << 16;                              \
          hu[e] = r; lu[e] = rl;                                            \
        }                                                                   \
        hw[p] = (hu[0] >> 16) | (hu[1] & 0xFFFF0000u);                      \
        lw[p] = (lu[0] >> 16) | (lu[1] & 0xFFFF0000u);                      \
      }                                                                     \
      short8 bhi = __builtin_bit_cast(short8, u32x4{hw[0], hw[1], hw[2], hw[3]}); \
      short8 blo = __builtin_bit_cast(short8, u32x4{lw[0], lw[1], lw[2], lw[3]}); \
      _Pragma("unroll")                                                     \
      for (int tm = 0; tm < 5; tm++) {                                      \
        short8 av = __builtin_bit_cast(short8, af[tm]);                     \
        acc[tm][tn] = __builtin_amdgcn_mfma_f32_16x16x32_bf16(av, bhi, acc[tm][tn], 0, 0, 0); \
        acc[tm][tn] = __builtin_amdgcn_mfma_f32_16x16x32_bf16(av, blo, acc[tm][tn], 0, 0, 0); \
      }                                                                     \
    }                                                                       \
  }

  LOADS(af0, wv0, sv0, 0);
  LOADS(af1, wv1, sv1, 1);
  int s = 0;
  for (; s + 2 < stages; s += 2) {
    COMPUTE(af0, wv0, sv0);
    LOADS(af0, wv0, sv0, s + 2);
    COMPUTE(af1, wv1, sv1);
    LOADS(af1, wv1, sv1, s + 3);
  }
  COMPUTE(af0, wv0, sv0);
  COMPUTE(af1, wv1, sv1);
#undef LOADS
#undef COMPUTE

#pragma unroll
  for (int tm = 0; tm < 5; tm++)
#pragma unroll
    for (int tn = 0; tn < 2; tn++) {
      int mrow = wid * 80 + tm * 16 + quad * 4;
      int ncol = nbase + tn * 16 + l15;
      float* dst = partial + ((size_t)ks * M_ + mrow) * H_ + ncol;
      dst[0 * H_] = acc[tm][tn].x;
      dst[1 * H_] = acc[tm][tn].y;
      dst[2 * H_] = acc[tm][tn].z;
      dst[3 * H_] = acc[tm][tn].w;
    }
}

// ---------------------------------------------------------------------------
// Kernel 3: deterministic reduction of K-split partials -> weighted [320][1024]
// Ascending-ks order (bit-identical across rounds). Also zeroes diag region.
// ---------------------------------------------------------------------------
__global__ __launch_bounds__(256) void reduce_w(const float* __restrict__ partial,
                                                float* __restrict__ weighted,
                                                float* __restrict__ out, int KS) {
  if (blockIdx.x == 0 && threadIdx.x < 30) out[327680 + threadIdx.x] = 0.f;
  int j = (blockIdx.x * 256 + threadIdx.x) * 4;
  f32x4 s = f32x4{0.f, 0.f, 0.f, 0.f};
  for (int k = 0; k < KS; k++) {
    f32x4 p = *(const f32x4*)&partial[(size_t)k * (M_ * H_) + j];
    s += p;
  }
  *(f32x4*)&weighted[j] = s;
}

// ---------------------------------------------------------------------------
// Kernel 4: LIF scan (unchanged — verified). Barrier-free; thread owns h and
// 4 batches; per-h threshold chain deterministic across lanes.
// ---------------------------------------------------------------------------
__global__ __launch_bounds__(64) void scan(const float* __restrict__ weighted,
                                           const float* __restrict__ threshold,
                                           const float* __restrict__ fre0,
                                           const float* __restrict__ p_tau_mem,
                                           const float* __restrict__ p_tau_syn,
                                           const float* __restrict__ p_target,
                                           const float* __restrict__ p_lr,
                                           float* __restrict__ out) {
  const int lane = threadIdx.x;
  const int hl = lane & 7, bg = lane >> 3;
  const int h = blockIdx.x * 8 + hl;
  const float alpha_mem = expf(-0.001f / p_tau_mem[0]);
  const float alpha_syn = expf(-0.001f / p_tau_syn[0]);
  const float target = p_target[0], lr = p_lr[0];
  float v[4], isyn[4];
#pragma unroll
  for (int j = 0; j < 4; j++) { v[j] = 0.f; isyn[j] = 0.f; }
  float fre = fre0[h];
  float thr = threshold[h];
  for (int t = 0; t < T_; t++) {
    float rsum = 0.f, vsum = 0.f;
#pragma unroll
    for (int j = 0; j < 4; j++) {
      int b = bg * 4 + j;
      float w_in = weighted[(size_t)(t * 32 + b) * H_ + h];
      isyn[j] = alpha_syn * isyn[j] + w_in;
      v[j] = alpha_mem * v[j] + isyn[j];
      float spike = (v[j] >= thr) ? 1.f : 0.f;
      v[j] -= spike * thr;
      out[(size_t)b * (H_ * T_) + (size_t)h * T_ + t] = spike;
      rsum += spike;
      vsum += v[j];
    }
    float r = rsum;
    r += __shfl_xor(r, 8);
    r += __shfl_xor(r, 16);
    r += __shfl_xor(r, 32);
    float rate = r * (1.f / 32.f);
    fre = 0.99f * fre + 0.01f * rate;
    thr = thr + lr * (fre - target);
    float vv = vsum, rr = rate, tt = thr;
#pragma unroll
    for (int off = 32; off >= 1; off >>= 1) {
      vv += __shfl_xor(vv, off);
      rr += __shfl_xor(rr, off);
      tt += __shfl_xor(tt, off);
    }
    if (lane == 0) {
      atomicAdd(&out[327680 + t], vv * (1.f / 32768.f));
      atomicAdd(&out[327690 + t], rr * (1.f / 8192.f));
      atomicAdd(&out[327700 + t], tt * (1.f / 8192.f));
    }
  }
}

// ---------------------------------------------------------------------------
extern "C" void kernel_launch(void* const* d_in, const int* in_sizes, int n_in,
                              void* d_out, int out_size, void* d_ws, size_t ws_size,
                              hipStream_t stream) {
  const float* spikes    = (const float*)d_in[0];
  const float* weight    = (const float*)d_in[1];
  const float* strength  = (const float*)d_in[2];
  const float* threshold = (const float*)d_in[3];
  const float* fre0      = (const float*)d_in[4];
  const float* tau_mem   = (const float*)d_in[5];
  const float* tau_syn   = (const float*)d_in[6];
  const float* target    = (const float*)d_in[7];
  const float* lr        = (const float*)d_in[8];
  float* out = (float*)d_out;

  const size_t sbf_bytes = (size_t)M_ * I_ * 2;     // 10.5 MB
  const size_t plane     = (size_t)I_ * H_ * 2;     // 33.6 MB per bf16 plane
  const size_t slice     = (size_t)M_ * H_ * 4;     // 1.31 MB per K-partial

  int KS = 32, kslog = 5;
  while (KS > 1 &&
         sbf_bytes + 2 * plane + (size_t)(KS + 1) * slice > ws_size) {
    KS >>= 1; kslog--;
  }
  bool use_planes =
      sbf_bytes + 2 * plane + (size_t)(KS + 1) * slice <= ws_size;

  if (use_planes) {
    uint16_t* Sbf   = (uint16_t*)d_ws;
    uint16_t* WhiT  = (uint16_t*)((char*)d_ws + sbf_bytes);
    uint16_t* WloT  = (uint16_t*)((char*)d_ws + sbf_bytes + plane);
    float* partial  = (float*)((char*)d_ws + sbf_bytes + 2 * plane);
    float* weighted = (float*)((char*)d_ws + sbf_bytes + 2 * plane +
                               (size_t)KS * slice);
    prep<<<1024 + (I_ / 64) * (H_ / 64), 256, 0, stream>>>(
        spikes, weight, strength, Sbf, WhiT, WloT);
    gemm_p<<<16 * KS, 256, 0, stream>>>(Sbf, WhiT, WloT, partial,
                                        I_ / KS, kslog);
    reduce_w<<<(M_ * H_) / 1024, 256, 0, stream>>>(partial, weighted, out, KS);
    scan<<<H_ / 8, 64, 0, stream>>>(weighted, threshold, fre0, tau_mem,
                                    tau_syn, target, lr, out);
  } else {
    // fallback: exact R6 structure (known-passing at ws >= 34 MB)
    int KSf = 16, kslogf = 4;
    while (KSf > 1 &&
           sbf_bytes + (size_t)(KSf + 1) * slice > ws_size) {
      KSf >>= 1; kslogf--;
    }
    uint16_t* Sbf   = (uint16_t*)d_ws;
    float* partial  = (float*)((char*)d_ws + sbf_bytes);
    float* weighted = (float*)((char*)d_ws + sbf_bytes + (size_t)KSf * slice);
    prep<<<1024, 256, 0, stream>>>(spikes, weight, strength, Sbf,
                                   (uint16_t*)nullptr, (uint16_t*)nullptr);
    gemm_fb<<<32 * KSf, 256, 0, stream>>>(Sbf, weight, strength, partial,
                                          I_ / KSf, kslogf);
    reduce_w<<<(M_ * H_) / 1024, 256, 0, stream>>>(partial, weighted, out, KSf);
    scan<<<H_ / 8, 64, 0, stream>>>(weighted, threshold, fre0, tau_mem,
                                    tau_syn, target, lr, out);
  }
}